// Round 11
// baseline (85.376 us; speedup 1.0000x reference)
//
#include <hip/hip_runtime.h>
#include <hip/hip_bf16.h>
#include <math.h>

// Sizes fixed by the reference: B=16, N=2048, F_in=F_out=64.
#define NB 16
#define NN 2048
#define NF 64
#define LOG2E 1.44269504f
#define ISPLIT 16         // k_colsum i-split factor
#define TBL_SPLIT 10      // isp < 10 -> table blocks, else trans blocks (0.625)

// g(t) nearest-neighbor table: t in [T_LO, T_HI], NT bins, value at bin midpoint.
#define NT 4096
#define T_LO (-40.0f)
#define T_HI (10.0f)
#define T_SCALE (NT / (T_HI - T_LO))         // 81.92 bins per unit t
#define Z_BIAS (-T_LO * T_SCALE)             // 3276.8
#define Z_MAX ((float)(NT - 1))

typedef __attribute__((ext_vector_type(8))) __bf16 bf16x8;
typedef __attribute__((ext_vector_type(8))) short  short8;
typedef __attribute__((ext_vector_type(4))) float  f32x4;

// Accurate g(t) = exp(sigmoid(leakyrelu(t))) — table build only.
__device__ __forceinline__ float gexact(float t) {
    float v = t >= 0.f ? t : 0.2f * t;
    float s = 1.f / (1.f + expf(-v));
    return expf(s);
}

// Exact trans-pipe eval from tp = -log2e * t (verified R1-R4).
__device__ __forceinline__ float evalg(float tp) {
    float u  = fminf(tp, 0.2f * tp);
    float ex = __builtin_amdgcn_exp2f(u);              // e^{-leaky}
    float s  = __builtin_amdgcn_rcpf(1.f + ex);        // sigmoid(leaky)
    return __builtin_amdgcn_exp2f(s * LOG2E);          // e^{sigmoid}
}

// LDS-pipe eval: z = t*T_SCALE + Z_BIAS (scale/bias pre-folded by caller).
__device__ __forceinline__ float tlookup(const float* __restrict__ stab, float z) {
    float zc = __builtin_amdgcn_fmed3f(z, 0.f, Z_MAX);
    return stab[(int)zc];
}

__device__ __forceinline__ float elu(float v) {
    return v > 0.f ? v : (__builtin_amdgcn_exp2f(v * LOG2E) - 1.f);
}

// ---------------- Pass A: Wh = h@W ; score pre-activations in BOTH domains.
// Blocks 0..15 additionally build the g-table.
__global__ __launch_bounds__(256) void k_prep(const float* __restrict__ h,
                                              const float* __restrict__ W,
                                              const float* __restrict__ a,
                                              float* __restrict__ wh,
                                              float* __restrict__ xs,
                                              float* __restrict__ ys,
                                              float* __restrict__ xs2,
                                              float* __restrict__ ys2,
                                              float* __restrict__ gtab) {
    __shared__ float hb[4][64];
    int w = threadIdx.x >> 6, lane = threadIdx.x & 63;
    int r = blockIdx.x * 4 + w;                 // row in [0, B*N)
    hb[w][lane] = h[r * 64 + lane];
    float acc = 0.f;
#pragma unroll
    for (int k = 0; k < 64; k++) acc = fmaf(hb[w][k], W[k * 64 + lane], acc);
    wh[r * 64 + lane] = acc;
    float xv = acc * a[lane];
    float yv = acc * a[64 + lane];
#pragma unroll
    for (int m = 32; m; m >>= 1) {
        xv += __shfl_xor(xv, m, 64);
        yv += __shfl_xor(yv, m, 64);
    }
    if (lane == 0) {
        xs[r]  = T_SCALE * xv;
        ys[r]  = T_SCALE * yv;
        xs2[r] = -LOG2E * xv;
        ys2[r] = -LOG2E * yv;
    }
    if (blockIdx.x < 16) {
        int i = blockIdx.x * 256 + threadIdx.x;     // [0, 4096)
        gtab[i] = gexact(T_LO + ((float)i + 0.5f) / T_SCALE);
    }
}

// ---------------- Pass B: column-sum partials. Block-level pipe specialization:
// isp < TBL_SPLIT -> all-table block; isp >= TBL_SPLIT -> all-trans block.
__global__ __launch_bounds__(256) void k_colsum(const float* __restrict__ xs,
                                                const float* __restrict__ ys,
                                                const float* __restrict__ xs2,
                                                const float* __restrict__ ys2,
                                                const float* __restrict__ gtab,
                                                float* __restrict__ dpart) {
    __shared__ float stab[NT];
    __shared__ float xb[128];
    int tid = threadIdx.x;
    int bx  = blockIdx.x;
    int jb  = bx & 7;            // N/256 = 8 j-chunks
    int isp = (bx >> 3) & 15;    // 16-way i split (128 i's each)
    int b   = bx >> 7;

    if (isp < TBL_SPLIT) {
        {   // stage table (16 KB) into LDS
            const float4* src = (const float4*)gtab;
            float4*       dst = (float4*)stab;
#pragma unroll
            for (int k = 0; k < NT / 4 / 256; k++) dst[tid + k * 256] = src[tid + k * 256];
        }
        if (tid < 128) xb[tid] = xs[b * NN + isp * 128 + tid];
        __syncthreads();
        float ypre = ys[b * NN + jb * 256 + tid] + Z_BIAS;
        float acc = 0.f;
#pragma unroll 4
        for (int i4 = 0; i4 < 32; i4++) {
            float4 xv = *reinterpret_cast<const float4*>(&xb[i4 * 4]);
            acc += tlookup(stab, xv.x + ypre);
            acc += tlookup(stab, xv.y + ypre);
            acc += tlookup(stab, xv.z + ypre);
            acc += tlookup(stab, xv.w + ypre);
        }
        dpart[isp * (NB * NN) + b * NN + jb * 256 + tid] = acc;
    } else {
        if (tid < 128) xb[tid] = xs2[b * NN + isp * 128 + tid];
        __syncthreads();
        float yv2 = ys2[b * NN + jb * 256 + tid];
        float acc = 0.f;
#pragma unroll 4
        for (int i4 = 0; i4 < 32; i4++) {
            float4 xv = *reinterpret_cast<const float4*>(&xb[i4 * 4]);
            acc += evalg(xv.x + yv2);
            acc += evalg(xv.y + yv2);
            acc += evalg(xv.z + yv2);
            acc += evalg(xv.w + yv2);
        }
        dpart[isp * (NB * NN) + b * NN + jb * 256 + tid] = acc;
    }
}

// ---------------- Pass B2 (fused D-reduce + V-frag): block per (b, ks) handles 32 rows.
// vfrag layout: [b][ks(64)][nt(4)][lane(64)] x 8 bf16; B-frag: col = lane&15, k = (lane>>4)*8 + e
__global__ __launch_bounds__(256) void k_vfragD(const float* __restrict__ wh,
                                                const float* __restrict__ dpart,
                                                uint4* __restrict__ vfrag) {
    __shared__ float pred[8][32];
    __shared__ float dinv[32];
    int bx = blockIdx.x;
    int ks = bx & 63;
    int b  = bx >> 6;
    int t  = threadIdx.x;
    {   // stage 1: 16 partials -> 8 in LDS
        int p = t >> 5, r = t & 31;
        int rowg = b * NN + ks * 32 + r;
        pred[p][r] = dpart[p * (NB * NN) + rowg] + dpart[(p + 8) * (NB * NN) + rowg];
    }
    __syncthreads();
    if (t < 32) {   // stage 2: finish the sum, invert
        float s = 0.f;
#pragma unroll
        for (int p2 = 0; p2 < 8; p2++) s += pred[p2][t];
        dinv[t] = __builtin_amdgcn_rcpf(s);
    }
    __syncthreads();
    int lane = t & 63, nt = t >> 6;
    int kg = lane >> 4, il = lane & 15;
    const float* whp = wh + (b * NN + ks * 32 + kg * 8) * 64 + nt * 16 + il;
    short8 o;
#pragma unroll
    for (int e = 0; e < 8; e++) {
        float v   = whp[e * 64] * dinv[kg * 8 + e];
        __bf16 bv = (__bf16)v;
        o[e]      = __builtin_bit_cast(short, bv);
    }
    vfrag[((b * 64 + ks) * 4 + nt) * 64 + lane] = __builtin_bit_cast(uint4, o);
}

// ---------------- Pass C: out = ELU( E @ V ), wave-specialized pipes.
// Block = 512 threads = 8 waves = 2 rg (16-row groups) x 4 kz (K-slices).
// K-slices: kz0 [0,18) kz1 [18,36) -> TABLE waves; kz2 [36,50) kz3 [50,64) -> TRANS waves.
// Per CU the resident table-waves and trans-waves are equal -> LDS and trans pipes
// loaded concurrently by different waves (no in-wave mixing).
// kz>0 waves dump f32 accs to LDS; kz==0 waves reduce + ELU + store.
// A-frag (16x32): row = lane&15, k = (lane>>4)*8 + e
// C/D frag:       col = lane&15, row = (lane>>4)*4 + reg   [verified layout]
__global__ __launch_bounds__(512, 4) void k_attn(const float* __restrict__ xs,
                                                 const float* __restrict__ ys,
                                                 const float* __restrict__ xs2,
                                                 const float* __restrict__ ys2,
                                                 const float* __restrict__ gtab,
                                                 const uint4* __restrict__ vfrag,
                                                 float* __restrict__ out) {
    __shared__ float stab[NT];
    __shared__ float red[2][3][16][65];   // [rg][kz-1][local row][col(+pad)]
    {   // stage table cooperatively (512 threads x 2 float4)
        const float4* src = (const float4*)gtab;
        float4*       dst = (float4*)stab;
#pragma unroll
        for (int k = 0; k < NT / 4 / 512; k++) dst[threadIdx.x + k * 512] = src[threadIdx.x + k * 512];
    }
    int b  = blockIdx.x >> 6;          // batch
    int ib = blockIdx.x & 63;          // 64 i-blocks of 32 rows
    int w  = threadIdx.x >> 6, lane = threadIdx.x & 63;
    int rg = w & 1, kz = w >> 1;
    int il = lane & 15, kg = lane >> 4;
    int ibase = ib * 32 + rg * 16;
    bool is_table = (kz < 2);
    int ks_lo = is_table ? 18 * kz : 36 + 14 * (kz - 2);
    int ks_hi = ks_lo + (is_table ? 18 : 14);

    float xv  = xs[b * NN + ibase + il] + Z_BIAS;   // z-domain (table)
    float xv2 = xs2[b * NN + ibase + il];           // tp-domain (trans)
    const float* ysb  = ys + b * NN;
    const float* ysb2 = ys2 + b * NN;
    const uint4* vfb  = vfrag + b * 16384 + lane;
    __syncthreads();

    f32x4 acc0 = {0.f, 0.f, 0.f, 0.f};
    f32x4 acc1 = {0.f, 0.f, 0.f, 0.f};
    f32x4 acc2 = {0.f, 0.f, 0.f, 0.f};
    f32x4 acc3 = {0.f, 0.f, 0.f, 0.f};

    if (is_table) {
        for (int ks = ks_lo; ks < ks_hi; ks++) {
            const float* yp = ysb + ks * 32 + kg * 8;
            float4 ya = *reinterpret_cast<const float4*>(yp);
            float4 yb = *reinterpret_cast<const float4*>(yp + 4);
            float wv[8];
            wv[0] = tlookup(stab, xv + ya.x);
            wv[1] = tlookup(stab, xv + ya.y);
            wv[2] = tlookup(stab, xv + ya.z);
            wv[3] = tlookup(stab, xv + ya.w);
            wv[4] = tlookup(stab, xv + yb.x);
            wv[5] = tlookup(stab, xv + yb.y);
            wv[6] = tlookup(stab, xv + yb.z);
            wv[7] = tlookup(stab, xv + yb.w);
            bf16x8 af;
#pragma unroll
            for (int e = 0; e < 8; e++) af[e] = (__bf16)wv[e];
            const uint4* vp = vfb + ks * 256;
            bf16x8 b0 = __builtin_bit_cast(bf16x8, vp[0]);
            bf16x8 b1 = __builtin_bit_cast(bf16x8, vp[64]);
            bf16x8 b2 = __builtin_bit_cast(bf16x8, vp[128]);
            bf16x8 b3 = __builtin_bit_cast(bf16x8, vp[192]);
            acc0 = __builtin_amdgcn_mfma_f32_16x16x32_bf16(af, b0, acc0, 0, 0, 0);
            acc1 = __builtin_amdgcn_mfma_f32_16x16x32_bf16(af, b1, acc1, 0, 0, 0);
            acc2 = __builtin_amdgcn_mfma_f32_16x16x32_bf16(af, b2, acc2, 0, 0, 0);
            acc3 = __builtin_amdgcn_mfma_f32_16x16x32_bf16(af, b3, acc3, 0, 0, 0);
        }
    } else {
        for (int ks = ks_lo; ks < ks_hi; ks++) {
            const float* yp2 = ysb2 + ks * 32 + kg * 8;
            float4 ya = *reinterpret_cast<const float4*>(yp2);
            float4 yb = *reinterpret_cast<const float4*>(yp2 + 4);
            float wv[8];
            wv[0] = evalg(xv2 + ya.x);
            wv[1] = evalg(xv2 + ya.y);
            wv[2] = evalg(xv2 + ya.z);
            wv[3] = evalg(xv2 + ya.w);
            wv[4] = evalg(xv2 + yb.x);
            wv[5] = evalg(xv2 + yb.y);
            wv[6] = evalg(xv2 + yb.z);
            wv[7] = evalg(xv2 + yb.w);
            bf16x8 af;
#pragma unroll
            for (int e = 0; e < 8; e++) af[e] = (__bf16)wv[e];
            const uint4* vp = vfb + ks * 256;
            bf16x8 b0 = __builtin_bit_cast(bf16x8, vp[0]);
            bf16x8 b1 = __builtin_bit_cast(bf16x8, vp[64]);
            bf16x8 b2 = __builtin_bit_cast(bf16x8, vp[128]);
            bf16x8 b3 = __builtin_bit_cast(bf16x8, vp[192]);
            acc0 = __builtin_amdgcn_mfma_f32_16x16x32_bf16(af, b0, acc0, 0, 0, 0);
            acc1 = __builtin_amdgcn_mfma_f32_16x16x32_bf16(af, b1, acc1, 0, 0, 0);
            acc2 = __builtin_amdgcn_mfma_f32_16x16x32_bf16(af, b2, acc2, 0, 0, 0);
            acc3 = __builtin_amdgcn_mfma_f32_16x16x32_bf16(af, b3, acc3, 0, 0, 0);
        }
    }

    if (kz > 0) {
#pragma unroll
        for (int r = 0; r < 4; r++) {
            float* rp = &red[rg][kz - 1][kg * 4 + r][il];
            rp[0]  = acc0[r];
            rp[16] = acc1[r];
            rp[32] = acc2[r];
            rp[48] = acc3[r];
        }
    }
    __syncthreads();
    if (kz == 0) {
        int rbase = b * NN + ibase + kg * 4;
#pragma unroll
        for (int r = 0; r < 4; r++) {
            const float* r0 = &red[rg][0][kg * 4 + r][il];
            const float* r1 = &red[rg][1][kg * 4 + r][il];
            const float* r2 = &red[rg][2][kg * 4 + r][il];
            float* orow = out + (rbase + r) * 64 + il;
            orow[0]  = elu(acc0[r] + r0[0]  + r1[0]  + r2[0]);
            orow[16] = elu(acc1[r] + r0[16] + r1[16] + r2[16]);
            orow[32] = elu(acc2[r] + r0[32] + r1[32] + r2[32]);
            orow[48] = elu(acc3[r] + r0[48] + r1[48] + r2[48]);
        }
    }
}

extern "C" void kernel_launch(void* const* d_in, const int* in_sizes, int n_in,
                              void* d_out, int out_size, void* d_ws, size_t ws_size,
                              hipStream_t stream) {
    const float* h = (const float*)d_in[0];
    const float* W = (const float*)d_in[1];
    const float* a = (const float*)d_in[2];
    float* out = (float*)d_out;

    // workspace layout (floats), ~15.5 MB total
    float*  wh    = (float*)d_ws;                  // B*N*64
    float*  xs    = wh + NB * NN * NF;             // B*N (z-domain)
    float*  ys    = xs + NB * NN;                  // B*N
    float*  xs2   = ys + NB * NN;                  // B*N (tp-domain)
    float*  ys2   = xs2 + NB * NN;                 // B*N
    float*  dpart = ys2 + NB * NN;                 // 16*B*N
    uint4*  vfrag = (uint4*)(dpart + ISPLIT * NB * NN);  // B*N*64 bf16 = 4 MB
    float*  gtab  = (float*)(vfrag + NB * NN * NF / 8);  // 4096 f32 = 16 KB

    k_prep<<<dim3(NB * NN / 4), dim3(256), 0, stream>>>(h, W, a, wh, xs, ys, xs2, ys2, gtab);
    k_colsum<<<dim3(NB * ISPLIT * (NN / 256)), dim3(256), 0, stream>>>(xs, ys, xs2, ys2, gtab, dpart);
    k_vfragD<<<dim3(NB * 64), dim3(256), 0, stream>>>(wh, dpart, vfrag);
    k_attn<<<dim3(NB * (NN / 32)), dim3(512), 0, stream>>>(xs, ys, xs2, ys2, gtab, vfrag, out);
}

// Round 12
// 52.790 us; speedup vs baseline: 1.6173x; 1.6173x over previous
//
#include <hip/hip_runtime.h>
#include <hip/hip_bf16.h>
#include <math.h>

// Sizes fixed by the reference: B=16, N=2048, F_in=F_out=64.
#define NB 16
#define NN 2048
#define NF 64
#define LOG2E 1.44269504f

// g(t) nearest-neighbor table: t in [T_LO, T_HI], NT bins, value at bin midpoint.
#define NT 4096
#define T_LO (-40.0f)
#define T_HI (10.0f)
#define T_SCALE (NT / (T_HI - T_LO))         // 81.92 bins per unit t
#define Z_BIAS (-T_LO * T_SCALE)             // 3276.8
#define Z_MAX ((float)(NT - 1))

// F/G sampling grids (in t-units of x resp. y): 512 points over [-96, 96), step 0.375.
#define MG 512
#define XG_LO (-96.0f)
#define DXG 0.375f
#define INV_DXG (1.0f / DXG)                 // 2.666667
#define U_BIAS (-XG_LO * INV_DXG)            // 256.0
#define U_MAX 510.999f                       // clamp so k+1 <= 511

typedef __attribute__((ext_vector_type(8))) __bf16 bf16x8;
typedef __attribute__((ext_vector_type(8))) short  short8;
typedef __attribute__((ext_vector_type(4))) float  f32x4;

// Accurate g(t) = exp(sigmoid(leakyrelu(t))) — table build only.
__device__ __forceinline__ float gexact(float t) {
    float v = t >= 0.f ? t : 0.2f * t;
    float s = 1.f / (1.f + expf(-v));
    return expf(s);
}

// LDS-pipe eval: z = t*T_SCALE + Z_BIAS (scale/bias pre-folded by caller).
__device__ __forceinline__ float tlookup(const float* __restrict__ stab, float z) {
    float zc = __builtin_amdgcn_fmed3f(z, 0.f, Z_MAX);
    return stab[(int)zc];
}

__device__ __forceinline__ float elu(float v) {
    return v > 0.f ? v : (__builtin_amdgcn_exp2f(v * LOG2E) - 1.f);
}

// ---------------- Pass A: Wh = h@W ; per-row scalars:
// xs,ys = T_SCALE * (x,y)  (z-domain for table evals)
// xs_u,ys_u = x/DXG + U_BIAS (grid coordinates for F/G interpolation)
// Blocks 0..15 additionally build the g-table.
__global__ __launch_bounds__(256) void k_prep(const float* __restrict__ h,
                                              const float* __restrict__ W,
                                              const float* __restrict__ a,
                                              float* __restrict__ wh,
                                              float* __restrict__ xs,
                                              float* __restrict__ ys,
                                              float* __restrict__ xs_u,
                                              float* __restrict__ ys_u,
                                              float* __restrict__ gtab) {
    __shared__ float hb[4][64];
    int w = threadIdx.x >> 6, lane = threadIdx.x & 63;
    int r = blockIdx.x * 4 + w;                 // row in [0, B*N)
    hb[w][lane] = h[r * 64 + lane];
    float acc = 0.f;
#pragma unroll
    for (int k = 0; k < 64; k++) acc = fmaf(hb[w][k], W[k * 64 + lane], acc);
    wh[r * 64 + lane] = acc;
    float xv = acc * a[lane];
    float yv = acc * a[64 + lane];
#pragma unroll
    for (int m = 32; m; m >>= 1) {
        xv += __shfl_xor(xv, m, 64);
        yv += __shfl_xor(yv, m, 64);
    }
    if (lane == 0) {
        xs[r]   = T_SCALE * xv;
        ys[r]   = T_SCALE * yv;
        xs_u[r] = xv * INV_DXG + U_BIAS;
        ys_u[r] = yv * INV_DXG + U_BIAS;
    }
    if (blockIdx.x < 16) {
        int i = blockIdx.x * 256 + threadIdx.x;     // [0, 4096)
        gtab[i] = gexact(T_LO + ((float)i + 0.5f) / T_SCALE);
    }
}

// ---------------- Pass B: F[b][m] = sum_i g(x_i + ym*), ym* = XG_LO + m*DXG.
// Block = (b, group of 4 m); wave per m; lane sums 32 i's; shuffle-reduce.
__global__ __launch_bounds__(256) void k_fbuild(const float* __restrict__ xs,
                                                const float* __restrict__ gtab,
                                                float* __restrict__ F) {
    __shared__ float stab[NT];
    __shared__ float xsb[NN];
    int tid = threadIdx.x;
    {   // stage table (16 KB) + the batch's xs row (8 KB)
        const float4* src = (const float4*)gtab;
        float4*       dst = (float4*)stab;
#pragma unroll
        for (int k = 0; k < NT / 4 / 256; k++) dst[tid + k * 256] = src[tid + k * 256];
    }
    int mg = blockIdx.x & 127;        // 128 m-groups of 4
    int b  = blockIdx.x >> 7;
    {
        const float4* src = (const float4*)(xs + b * NN);
        float4*       dst = (float4*)xsb;
#pragma unroll
        for (int k = 0; k < NN / 4 / 256; k++) dst[tid + k * 256] = src[tid + k * 256];
    }
    __syncthreads();
    int w = tid >> 6, lane = tid & 63;
    int m = mg * 4 + w;
    float ymb = (XG_LO + (float)m * DXG) * T_SCALE + Z_BIAS;
    float acc = 0.f;
#pragma unroll 8
    for (int i8 = 0; i8 < NN / 64; i8++)
        acc += tlookup(stab, xsb[i8 * 64 + lane] + ymb);
#pragma unroll
    for (int s = 32; s; s >>= 1) acc += __shfl_xor(acc, s, 64);
    if (lane == 0) F[b * MG + m] = acc;
}

// ---------------- Pass B2: V = Wh / D -> bf16 MFMA B-fragments; D = lerp(F, y_j).
// vfrag layout: [b][ks(64)][nt(4)][lane(64)] x 8 bf16; B-frag: col = lane&15, k = (lane>>4)*8 + e
__global__ __launch_bounds__(256) void k_vfragD(const float* __restrict__ wh,
                                                const float* __restrict__ F,
                                                const float* __restrict__ ys_u,
                                                uint4* __restrict__ vfrag) {
    __shared__ float dinv[32];
    int bx = blockIdx.x;
    int ks = bx & 63;
    int b  = bx >> 6;
    int t  = threadIdx.x;
    if (t < 32) {
        float u  = __builtin_amdgcn_fmed3f(ys_u[b * NN + ks * 32 + t], 0.f, U_MAX);
        int   k  = (int)u;
        float fr = u - (float)k;
        const float* Fb = F + b * MG;
        float d  = fmaf(Fb[k + 1] - Fb[k], fr, Fb[k]);
        dinv[t]  = __builtin_amdgcn_rcpf(d);
    }
    __syncthreads();
    int lane = t & 63, nt = t >> 6;
    int kg = lane >> 4, il = lane & 15;
    const float* whp = wh + (b * NN + ks * 32 + kg * 8) * 64 + nt * 16 + il;
    short8 o;
#pragma unroll
    for (int e = 0; e < 8; e++) {
        float v   = whp[e * 64] * dinv[kg * 8 + e];
        __bf16 bv = (__bf16)v;
        o[e]      = __builtin_bit_cast(short, bv);
    }
    vfrag[((b * 64 + ks) * 4 + nt) * 64 + lane] = __builtin_bit_cast(uint4, o);
}

// ---------------- Pass C: G[b][m][f] = sum_j g(xm* + y_j) * V[j][f]  (f32, no ELU).
// 512 blocks: (b, ib) with 16 sample-rows each; 4 kz waves split the 64 K-steps;
// kz>0 dump to LDS, kz==0 reduces + stores. Same MFMA structure as R5 k_attn.
// A-frag (16x32): row = lane&15, k = (lane>>4)*8 + e
// C/D frag:       col = lane&15, row = (lane>>4)*4 + reg   [verified layout]
__global__ __launch_bounds__(256) void k_gbuild(const float* __restrict__ ys,
                                                const float* __restrict__ gtab,
                                                const uint4* __restrict__ vfrag,
                                                float* __restrict__ G) {
    __shared__ float stab[NT];
    __shared__ float red[3][16][65];   // [kz-1][local row][col(+pad)]
    {   // stage table (16 KB)
        const float4* src = (const float4*)gtab;
        float4*       dst = (float4*)stab;
#pragma unroll
        for (int k = 0; k < NT / 4 / 256; k++) dst[threadIdx.x + k * 256] = src[threadIdx.x + k * 256];
    }
    int b  = blockIdx.x >> 5;          // batch
    int ib = blockIdx.x & 31;          // 32 m-blocks of 16 sample rows
    int kz = threadIdx.x >> 6, lane = threadIdx.x & 63;
    int il = lane & 15, kg = lane >> 4;
    int mbase = ib * 16;

    // sample-point x, pre-folded into z-domain with bias
    float xgb = (XG_LO + (float)(mbase + il) * DXG) * T_SCALE + Z_BIAS;
    const float* ysb = ys + b * NN;
    const uint4* vfb = vfrag + b * 16384 + lane;
    __syncthreads();

    f32x4 acc0 = {0.f, 0.f, 0.f, 0.f};
    f32x4 acc1 = {0.f, 0.f, 0.f, 0.f};
    f32x4 acc2 = {0.f, 0.f, 0.f, 0.f};
    f32x4 acc3 = {0.f, 0.f, 0.f, 0.f};

    for (int ks = kz * 16; ks < kz * 16 + 16; ks++) {
        const float* yp = ysb + ks * 32 + kg * 8;
        float4 ya = *reinterpret_cast<const float4*>(yp);
        float4 yb = *reinterpret_cast<const float4*>(yp + 4);
        float wv[8];
        wv[0] = tlookup(stab, xgb + ya.x);
        wv[1] = tlookup(stab, xgb + ya.y);
        wv[2] = tlookup(stab, xgb + ya.z);
        wv[3] = tlookup(stab, xgb + ya.w);
        wv[4] = tlookup(stab, xgb + yb.x);
        wv[5] = tlookup(stab, xgb + yb.y);
        wv[6] = tlookup(stab, xgb + yb.z);
        wv[7] = tlookup(stab, xgb + yb.w);
        bf16x8 af;
#pragma unroll
        for (int e = 0; e < 8; e++) af[e] = (__bf16)wv[e];

        const uint4* vp = vfb + ks * 256;
        bf16x8 b0 = __builtin_bit_cast(bf16x8, vp[0]);
        bf16x8 b1 = __builtin_bit_cast(bf16x8, vp[64]);
        bf16x8 b2 = __builtin_bit_cast(bf16x8, vp[128]);
        bf16x8 b3 = __builtin_bit_cast(bf16x8, vp[192]);

        acc0 = __builtin_amdgcn_mfma_f32_16x16x32_bf16(af, b0, acc0, 0, 0, 0);
        acc1 = __builtin_amdgcn_mfma_f32_16x16x32_bf16(af, b1, acc1, 0, 0, 0);
        acc2 = __builtin_amdgcn_mfma_f32_16x16x32_bf16(af, b2, acc2, 0, 0, 0);
        acc3 = __builtin_amdgcn_mfma_f32_16x16x32_bf16(af, b3, acc3, 0, 0, 0);
    }

    if (kz > 0) {
#pragma unroll
        for (int r = 0; r < 4; r++) {
            float* rp = &red[kz - 1][kg * 4 + r][il];
            rp[0]  = acc0[r];
            rp[16] = acc1[r];
            rp[32] = acc2[r];
            rp[48] = acc3[r];
        }
    }
    __syncthreads();
    if (kz == 0) {
        int gbase = (b * MG + mbase + kg * 4) * 64 + il;
#pragma unroll
        for (int r = 0; r < 4; r++) {
            const float* r0 = &red[0][kg * 4 + r][il];
            const float* r1 = &red[1][kg * 4 + r][il];
            const float* r2 = &red[2][kg * 4 + r][il];
            float* grow = G + gbase + r * 64;
            grow[0]  = acc0[r] + r0[0]  + r1[0]  + r2[0];
            grow[16] = acc1[r] + r0[16] + r1[16] + r2[16];
            grow[32] = acc2[r] + r0[32] + r1[32] + r2[32];
            grow[48] = acc3[r] + r0[48] + r1[48] + r2[48];
        }
    }
}

// ---------------- Pass D: out[i][f] = ELU( lerp_x(G_b)(x_i)[f] ). Wave per row.
__global__ __launch_bounds__(256) void k_apply(const float* __restrict__ xs_u,
                                               const float* __restrict__ G,
                                               float* __restrict__ out) {
    int w = threadIdx.x >> 6, f = threadIdx.x & 63;
    int r = blockIdx.x * 4 + w;                  // row in [0, B*N)
    int b = r >> 11;
    float u  = __builtin_amdgcn_fmed3f(xs_u[r], 0.f, U_MAX);
    int   k  = (int)u;
    float fr = u - (float)k;
    const float* Gb = G + (b * MG + k) * 64;
    float g0 = Gb[f];
    float g1 = Gb[64 + f];
    out[r * 64 + f] = elu(fmaf(g1 - g0, fr, g0));
}

extern "C" void kernel_launch(void* const* d_in, const int* in_sizes, int n_in,
                              void* d_out, int out_size, void* d_ws, size_t ws_size,
                              hipStream_t stream) {
    const float* h = (const float*)d_in[0];
    const float* W = (const float*)d_in[1];
    const float* a = (const float*)d_in[2];
    float* out = (float*)d_out;

    // workspace layout (floats), ~15 MB total
    float*  wh    = (float*)d_ws;                  // B*N*64 = 2,097,152 f
    float*  xs    = wh + NB * NN * NF;             // B*N (z-scaled x)
    float*  ys    = xs + NB * NN;                  // B*N (z-scaled y)
    float*  xs_u  = ys + NB * NN;                  // B*N (grid coords of x)
    float*  ys_u  = xs_u + NB * NN;                // B*N (grid coords of y)
    float*  F     = ys_u + NB * NN;                // B*MG = 8,192 f
    float*  G     = F + NB * MG;                   // B*MG*64 = 524,288 f (2 MB)
    uint4*  vfrag = (uint4*)(G + NB * MG * NF);    // B*N*64 bf16 = 4 MB
    float*  gtab  = (float*)(vfrag + NB * NN * NF / 8);  // 4096 f32 = 16 KB

    k_prep<<<dim3(NB * NN / 4), dim3(256), 0, stream>>>(h, W, a, wh, xs, ys, xs_u, ys_u, gtab);
    k_fbuild<<<dim3(NB * (MG / 4)), dim3(256), 0, stream>>>(xs, gtab, F);
    k_vfragD<<<dim3(NB * 64), dim3(256), 0, stream>>>(wh, F, ys_u, vfrag);
    k_gbuild<<<dim3(NB * (MG / 16)), dim3(256), 0, stream>>>(ys, gtab, vfrag, G);
    k_apply<<<dim3(NB * NN / 4), dim3(256), 0, stream>>>(xs_u, G, out);
}